// Round 1
// baseline (367.529 us; speedup 1.0000x reference)
//
#include <hip/hip_runtime.h>
#include <math.h>

#define NROWS 8192
#define DIM   128            // row length (fp32 in, bf16 staged)
#define NT    64             // 8192 / 128 tiles per side
#define TRI   2080           // NT*(NT+1)/2 upper-tri tiles incl diag

typedef __attribute__((ext_vector_type(8))) __bf16 bf16x8;
typedef __attribute__((ext_vector_type(4))) float  f32x4;

__device__ __forceinline__ unsigned short f2bf(float f) {
    unsigned int u = __float_as_uint(f);
    u += 0x7fffu + ((u >> 16) & 1u);   // round-to-nearest-even
    return (unsigned short)(u >> 16);
}

__global__ void zero_acc(double* acc) {
    if (threadIdx.x < 4) acc[threadIdx.x] = 0.0;
}

// One wave per row: normalize q-row and k-row, write bf16, accumulate align.
__global__ __launch_bounds__(256) void norm_kernel(
        const float* __restrict__ q, const float* __restrict__ k,
        unsigned int* __restrict__ qn, unsigned int* __restrict__ kn,
        double* __restrict__ acc) {
    int wave = threadIdx.x >> 6;
    int lane = threadIdx.x & 63;
    int row  = blockIdx.x * 4 + wave;      // grid = 2048 blocks * 4 waves

    const float2 qv = reinterpret_cast<const float2*>(q)[row * 64 + lane];
    const float2 kv = reinterpret_cast<const float2*>(k)[row * 64 + lane];

    float sq = qv.x * qv.x + qv.y * qv.y;
    float sk = kv.x * kv.x + kv.y * kv.y;
    #pragma unroll
    for (int off = 32; off; off >>= 1) {
        sq += __shfl_xor(sq, off);
        sk += __shfl_xor(sk, off);
    }
    float qi = 1.0f / fmaxf(sqrtf(sq), 1e-12f);
    float ki = 1.0f / fmaxf(sqrtf(sk), 1e-12f);
    float qx = qv.x * qi, qy = qv.y * qi;
    float kx = kv.x * ki, ky = kv.y * ki;

    qn[row * 64 + lane] = (unsigned int)f2bf(qx) | ((unsigned int)f2bf(qy) << 16);
    kn[row * 64 + lane] = (unsigned int)f2bf(kx) | ((unsigned int)f2bf(ky) << 16);

    float dx = qx - kx, dy = qy - ky;
    float d2 = dx * dx + dy * dy;
    #pragma unroll
    for (int off = 32; off; off >>= 1) d2 += __shfl_xor(d2, off);
    if (lane == 0) atomicAdd(acc + 0, (double)d2);
}

// One 128x128 Gram tile per block (upper-triangular tiles only).
// acc[1] += sum_{i<j in tile} exp(-2*max(2-2*g,0)) for q; acc[2] for k.
__global__ __launch_bounds__(256) void gram_kernel(
        const uint4* __restrict__ qn, const uint4* __restrict__ kn,
        double* __restrict__ acc) {
    __shared__ uint4 lds[4096];            // A: [0,2048) B: [2048,4096), 64 KiB

    int bid = blockIdx.x;
    int mat = 0, t = bid;
    if (t >= TRI) { mat = 1; t -= TRI; }
    int ti = 0, rem = t;
    while (rem >= NT - ti) { rem -= NT - ti; ++ti; }
    int tj = ti + rem;
    const uint4* __restrict__ x = mat ? kn : qn;
    double* S = acc + 1 + mat;

    int tid = threadIdx.x;
    // ---- stage both row-panels, XOR-swizzled (slot ^ (row&7)) ----
    {
        int s = tid & 15;                  // 16B slot within 256B row
        int rb = tid >> 4;                 // 0..15
        #pragma unroll
        for (int it = 0; it < 8; ++it) {
            int r = it * 16 + rb;
            int sw = s ^ (r & 7);
            lds[r * 16 + sw]        = x[(ti * 128 + r) * 16 + s];
            lds[2048 + r * 16 + sw] = x[(tj * 128 + r) * 16 + s];
        }
    }
    __syncthreads();

    int wid = tid >> 6, lane = tid & 63;
    int wr = wid >> 1, wc = wid & 1;       // 2x2 wave grid, each 64x64
    int lr = lane & 15, lg = lane >> 4;    // frag row / k-group

    f32x4 c[4][4];
    #pragma unroll
    for (int m = 0; m < 4; ++m)
        #pragma unroll
        for (int n = 0; n < 4; ++n)
            c[m][n] = (f32x4){0.f, 0.f, 0.f, 0.f};

    #pragma unroll
    for (int ks = 0; ks < 4; ++ks) {       // K = 128 = 4 * 32
        int slot = ks * 4 + lg;
        bf16x8 a[4], b[4];
        #pragma unroll
        for (int m = 0; m < 4; ++m) {
            int r = wr * 64 + m * 16 + lr;
            a[m] = *reinterpret_cast<const bf16x8*>(&lds[r * 16 + (slot ^ (r & 7))]);
        }
        #pragma unroll
        for (int n = 0; n < 4; ++n) {
            int r = wc * 64 + n * 16 + lr;
            b[n] = *reinterpret_cast<const bf16x8*>(&lds[2048 + r * 16 + (slot ^ (r & 7))]);
        }
        #pragma unroll
        for (int m = 0; m < 4; ++m)
            #pragma unroll
            for (int n = 0; n < 4; ++n)
                c[m][n] = __builtin_amdgcn_mfma_f32_16x16x32_bf16(a[m], b[n], c[m][n], 0, 0, 0);
    }

    // ---- epilogue: e = exp(-2*max(2-2g,0)) = exp2(min(4*log2e*(g-1),0)) ----
    const float C1 = 4.0f * 1.4426950408889634f;
    const float C0 = -4.0f * 1.4426950408889634f;
    bool diag = (ti == tj);
    float psum = 0.0f;
    int crow0 = wr * 64 + lg * 4;          // C layout: row=(lane>>4)*4+reg
    int ccol0 = wc * 64 + lr;              //           col=lane&15
    #pragma unroll
    for (int m = 0; m < 4; ++m)
        #pragma unroll
        for (int n = 0; n < 4; ++n)
            #pragma unroll
            for (int r = 0; r < 4; ++r) {
                float g = c[m][n][r];
                float w = fminf(fmaf(g, C1, C0), 0.0f);
                float e = exp2f(w);
                if (diag) {
                    int lrow = crow0 + m * 16 + r;
                    int lcol = ccol0 + n * 16;
                    e = (lcol > lrow) ? e : 0.0f;
                }
                psum += e;
            }
    #pragma unroll
    for (int off = 32; off; off >>= 1) psum += __shfl_xor(psum, off);
    if (lane == 0) atomicAdd(S, (double)psum);
}

__global__ void finalize(const double* __restrict__ acc, float* __restrict__ out) {
    const double npairs = (double)NROWS * (NROWS - 1) / 2.0;
    double align = acc[0] / (double)NROWS;
    double lq = log(acc[1] / npairs);
    double lk = log(acc[2] / npairs);
    out[0] = (float)(align + 0.5 * (lq + lk));   // LAMDA = 1
}

extern "C" void kernel_launch(void* const* d_in, const int* in_sizes, int n_in,
                              void* d_out, int out_size, void* d_ws, size_t ws_size,
                              hipStream_t stream) {
    const float* q = (const float*)d_in[0];
    const float* k = (const float*)d_in[1];
    char* ws = (char*)d_ws;
    unsigned int* qn = (unsigned int*)ws;                          // 2 MiB bf16
    unsigned int* kn = (unsigned int*)(ws + (size_t)2 * 1024 * 1024);
    double*      acc = (double*)(ws + (size_t)4 * 1024 * 1024);    // 3 doubles
    float* out = (float*)d_out;

    zero_acc<<<1, 64, 0, stream>>>(acc);
    norm_kernel<<<NROWS / 4, 256, 0, stream>>>(q, k, qn, kn, acc);
    gram_kernel<<<2 * TRI, 256, 0, stream>>>((const uint4*)qn, (const uint4*)kn, acc);
    finalize<<<1, 1, 0, stream>>>(acc, out);
}

// Round 2
// 111.665 us; speedup vs baseline: 3.2913x; 3.2913x over previous
//
#include <hip/hip_runtime.h>
#include <math.h>

#define NROWS 8192
#define DIM   128            // row length (fp32 in, bf16 staged)
#define NT    64             // 8192 / 128 tiles per side
#define TRI   2080           // NT*(NT+1)/2 upper-tri tiles incl diag

typedef __attribute__((ext_vector_type(8))) __bf16 bf16x8;
typedef __attribute__((ext_vector_type(4))) float  f32x4;

__device__ __forceinline__ unsigned short f2bf(float f) {
    unsigned int u = __float_as_uint(f);
    u += 0x7fffu + ((u >> 16) & 1u);   // round-to-nearest-even
    return (unsigned short)(u >> 16);
}

// One wave per row: normalize q-row and k-row, write bf16, per-block align partial.
__global__ __launch_bounds__(256) void norm_kernel(
        const float* __restrict__ q, const float* __restrict__ k,
        unsigned int* __restrict__ qn, unsigned int* __restrict__ kn,
        float* __restrict__ align_part) {
    int wave = threadIdx.x >> 6;
    int lane = threadIdx.x & 63;
    int row  = blockIdx.x * 4 + wave;      // grid = 2048 blocks * 4 waves

    const float2 qv = reinterpret_cast<const float2*>(q)[row * 64 + lane];
    const float2 kv = reinterpret_cast<const float2*>(k)[row * 64 + lane];

    float sq = qv.x * qv.x + qv.y * qv.y;
    float sk = kv.x * kv.x + kv.y * kv.y;
    #pragma unroll
    for (int off = 32; off; off >>= 1) {
        sq += __shfl_xor(sq, off);
        sk += __shfl_xor(sk, off);
    }
    float qi = 1.0f / fmaxf(sqrtf(sq), 1e-12f);
    float ki = 1.0f / fmaxf(sqrtf(sk), 1e-12f);
    float qx = qv.x * qi, qy = qv.y * qi;
    float kx = kv.x * ki, ky = kv.y * ki;

    qn[row * 64 + lane] = (unsigned int)f2bf(qx) | ((unsigned int)f2bf(qy) << 16);
    kn[row * 64 + lane] = (unsigned int)f2bf(kx) | ((unsigned int)f2bf(ky) << 16);

    float dx = qx - kx, dy = qy - ky;
    float d2 = dx * dx + dy * dy;
    #pragma unroll
    for (int off = 32; off; off >>= 1) d2 += __shfl_xor(d2, off);

    __shared__ float red[4];
    if (lane == 0) red[wave] = d2;
    __syncthreads();
    if (threadIdx.x == 0)
        align_part[blockIdx.x] = red[0] + red[1] + red[2] + red[3];
}

// One 128x128 Gram tile per block (upper-triangular tiles only).
// unif_part[bid] = sum_{i<j in tile} exp(-2*max(2-2*g,0))
__global__ __launch_bounds__(256) void gram_kernel(
        const uint4* __restrict__ qn, const uint4* __restrict__ kn,
        float* __restrict__ unif_part) {
    __shared__ uint4 lds[4096];            // A: [0,2048) B: [2048,4096), 64 KiB
    __shared__ float red[4];

    int bid = blockIdx.x;
    int mat = 0, t = bid;
    if (t >= TRI) { mat = 1; t -= TRI; }
    int ti = 0, rem = t;
    while (rem >= NT - ti) { rem -= NT - ti; ++ti; }
    int tj = ti + rem;
    const uint4* __restrict__ x = mat ? kn : qn;

    int tid = threadIdx.x;
    // ---- stage both row-panels, XOR-swizzled (slot ^ (row&7)) ----
    {
        int s = tid & 15;                  // 16B slot within 256B row
        int rb = tid >> 4;                 // 0..15
        #pragma unroll
        for (int it = 0; it < 8; ++it) {
            int r = it * 16 + rb;
            int sw = s ^ (r & 7);
            lds[r * 16 + sw]        = x[(ti * 128 + r) * 16 + s];
            lds[2048 + r * 16 + sw] = x[(tj * 128 + r) * 16 + s];
        }
    }
    __syncthreads();

    int wid = tid >> 6, lane = tid & 63;
    int wr = wid >> 1, wc = wid & 1;       // 2x2 wave grid, each 64x64
    int lr = lane & 15, lg = lane >> 4;    // frag row / k-group

    f32x4 c[4][4];
    #pragma unroll
    for (int m = 0; m < 4; ++m)
        #pragma unroll
        for (int n = 0; n < 4; ++n)
            c[m][n] = (f32x4){0.f, 0.f, 0.f, 0.f};

    #pragma unroll
    for (int ks = 0; ks < 4; ++ks) {       // K = 128 = 4 * 32
        int slot = ks * 4 + lg;
        bf16x8 a[4], b[4];
        #pragma unroll
        for (int m = 0; m < 4; ++m) {
            int r = wr * 64 + m * 16 + lr;
            a[m] = *reinterpret_cast<const bf16x8*>(&lds[r * 16 + (slot ^ (r & 7))]);
        }
        #pragma unroll
        for (int n = 0; n < 4; ++n) {
            int r = wc * 64 + n * 16 + lr;
            b[n] = *reinterpret_cast<const bf16x8*>(&lds[2048 + r * 16 + (slot ^ (r & 7))]);
        }
        #pragma unroll
        for (int m = 0; m < 4; ++m)
            #pragma unroll
            for (int n = 0; n < 4; ++n)
                c[m][n] = __builtin_amdgcn_mfma_f32_16x16x32_bf16(a[m], b[n], c[m][n], 0, 0, 0);
    }

    // ---- epilogue: e = exp(-2*max(2-2g,0)) = exp2(min(4*log2e*(g-1),0)) ----
    const float C1 = 4.0f * 1.4426950408889634f;
    const float C0 = -4.0f * 1.4426950408889634f;
    bool diag = (ti == tj);
    float psum = 0.0f;
    int crow0 = wr * 64 + lg * 4;          // C layout: row=(lane>>4)*4+reg
    int ccol0 = wc * 64 + lr;              //           col=lane&15
    #pragma unroll
    for (int m = 0; m < 4; ++m)
        #pragma unroll
        for (int n = 0; n < 4; ++n)
            #pragma unroll
            for (int r = 0; r < 4; ++r) {
                float g = c[m][n][r];
                float w = fminf(fmaf(g, C1, C0), 0.0f);
                float e = exp2f(w);
                if (diag) {
                    int lrow = crow0 + m * 16 + r;
                    int lcol = ccol0 + n * 16;
                    e = (lcol > lrow) ? e : 0.0f;
                }
                psum += e;
            }
    #pragma unroll
    for (int off = 32; off; off >>= 1) psum += __shfl_xor(psum, off);

    if (lane == 0) red[wid] = psum;
    __syncthreads();
    if (tid == 0)
        unif_part[bid] = red[0] + red[1] + red[2] + red[3];
}

// Single block: sum all partials in double, emit final scalar.
__global__ __launch_bounds__(256) void finalize(
        const float* __restrict__ align_part,   // [2048]
        const float* __restrict__ unif_part,    // [2*TRI]
        float* __restrict__ out) {
    int tid = threadIdx.x;
    double a = 0.0, qs = 0.0, ks = 0.0;
    for (int i = tid; i < 2048; i += 256) a  += (double)align_part[i];
    for (int i = tid; i < TRI;  i += 256) qs += (double)unif_part[i];
    for (int i = tid; i < TRI;  i += 256) ks += (double)unif_part[TRI + i];

    __shared__ double sa[256], sq[256], sk[256];
    sa[tid] = a; sq[tid] = qs; sk[tid] = ks;
    __syncthreads();
    for (int s = 128; s; s >>= 1) {
        if (tid < s) {
            sa[tid] += sa[tid + s];
            sq[tid] += sq[tid + s];
            sk[tid] += sk[tid + s];
        }
        __syncthreads();
    }
    if (tid == 0) {
        const double npairs = (double)NROWS * (NROWS - 1) / 2.0;
        double align = sa[0] / (double)NROWS;
        double lq = log(sq[0] / npairs);
        double lk = log(sk[0] / npairs);
        out[0] = (float)(align + 0.5 * (lq + lk));   // LAMDA = 1
    }
}

extern "C" void kernel_launch(void* const* d_in, const int* in_sizes, int n_in,
                              void* d_out, int out_size, void* d_ws, size_t ws_size,
                              hipStream_t stream) {
    const float* q = (const float*)d_in[0];
    const float* k = (const float*)d_in[1];
    char* ws = (char*)d_ws;
    unsigned int* qn = (unsigned int*)ws;                          // 2 MiB bf16
    unsigned int* kn = (unsigned int*)(ws + (size_t)2 * 1024 * 1024);
    float* align_part = (float*)(ws + (size_t)4 * 1024 * 1024);            // 2048 f32
    float* unif_part  = (float*)(ws + (size_t)4 * 1024 * 1024 + 16384);    // 4160 f32
    float* out = (float*)d_out;

    norm_kernel<<<NROWS / 4, 256, 0, stream>>>(q, k, qn, kn, align_part);
    gram_kernel<<<2 * TRI, 256, 0, stream>>>((const uint4*)qn, (const uint4*)kn, unif_part);
    finalize<<<1, 256, 0, stream>>>(align_part, unif_part, out);
}

// Round 3
// 106.799 us; speedup vs baseline: 3.4413x; 1.0456x over previous
//
#include <hip/hip_runtime.h>
#include <math.h>

#define NROWS 8192
#define DIM   128            // row length (fp32 in, bf16 staged)
#define NT    64             // 8192 / 128 tiles per side
#define TRI   2080           // NT*(NT+1)/2 upper-tri tiles incl diag

typedef __attribute__((ext_vector_type(8))) __bf16 bf16x8;
typedef __attribute__((ext_vector_type(4))) float  f32x4;
typedef __attribute__((ext_vector_type(2))) float  f32x2;

__device__ __forceinline__ unsigned short f2bf(float f) {
    unsigned int u = __float_as_uint(f);
    u += 0x7fffu + ((u >> 16) & 1u);   // round-to-nearest-even
    return (unsigned short)(u >> 16);
}

// One wave per row: normalize q-row and k-row, write bf16, per-block align partial.
__global__ __launch_bounds__(256) void norm_kernel(
        const float* __restrict__ q, const float* __restrict__ k,
        unsigned int* __restrict__ qn, unsigned int* __restrict__ kn,
        float* __restrict__ align_part) {
    int wave = threadIdx.x >> 6;
    int lane = threadIdx.x & 63;
    int row  = blockIdx.x * 4 + wave;      // grid = 2048 blocks * 4 waves

    const float2 qv = reinterpret_cast<const float2*>(q)[row * 64 + lane];
    const float2 kv = reinterpret_cast<const float2*>(k)[row * 64 + lane];

    float sq = qv.x * qv.x + qv.y * qv.y;
    float sk = kv.x * kv.x + kv.y * kv.y;
    #pragma unroll
    for (int off = 32; off; off >>= 1) {
        sq += __shfl_xor(sq, off);
        sk += __shfl_xor(sk, off);
    }
    float qi = 1.0f / fmaxf(sqrtf(sq), 1e-12f);
    float ki = 1.0f / fmaxf(sqrtf(sk), 1e-12f);
    float qx = qv.x * qi, qy = qv.y * qi;
    float kx = kv.x * ki, ky = kv.y * ki;

    qn[row * 64 + lane] = (unsigned int)f2bf(qx) | ((unsigned int)f2bf(qy) << 16);
    kn[row * 64 + lane] = (unsigned int)f2bf(kx) | ((unsigned int)f2bf(ky) << 16);

    float dx = qx - kx, dy = qy - ky;
    float d2 = dx * dx + dy * dy;
    #pragma unroll
    for (int off = 32; off; off >>= 1) d2 += __shfl_xor(d2, off);

    __shared__ float red[4];
    if (lane == 0) red[wave] = d2;
    __syncthreads();
    if (threadIdx.x == 0)
        align_part[blockIdx.x] = red[0] + red[1] + red[2] + red[3];
}

// One 128x128 Gram tile per block (upper-triangular tiles only), 8 waves.
// Wave grid 2x4: each wave owns 64 rows x 32 cols (c[4][2] fragments).
// unif_part[bid] = sum_{i<j in tile} exp(-2*(2-2*g))   (clamp dropped: off-diag g << 1)
__global__ __launch_bounds__(512) void gram_kernel(
        const uint4* __restrict__ qn, const uint4* __restrict__ kn,
        float* __restrict__ unif_part) {
    __shared__ uint4 lds[4096];            // A: [0,2048) B: [2048,4096), 64 KiB
    __shared__ float red[8];

    int bid = blockIdx.x;
    int mat = 0, t = bid;
    if (t >= TRI) { mat = 1; t -= TRI; }
    int ti = 0, rem = t;
    while (rem >= NT - ti) { rem -= NT - ti; ++ti; }
    int tj = ti + rem;
    const uint4* __restrict__ x = mat ? kn : qn;

    int tid = threadIdx.x;
    // ---- stage both row-panels, XOR-swizzled (slot ^ (row&7)) ----
    {
        int s = tid & 15;                  // 16B slot within 256B row
        int rb = tid >> 4;                 // 0..31
        #pragma unroll
        for (int it = 0; it < 4; ++it) {
            int r = it * 32 + rb;
            int sw = s ^ (r & 7);
            lds[r * 16 + sw]        = x[(ti * 128 + r) * 16 + s];
            lds[2048 + r * 16 + sw] = x[(tj * 128 + r) * 16 + s];
        }
    }
    __syncthreads();

    int wid = tid >> 6, lane = tid & 63;
    int wr = wid >> 2, wc = wid & 3;       // 2x4 wave grid, each 64x32
    int lr = lane & 15, lg = lane >> 4;    // frag row / k-group

    f32x4 c[4][2];
    #pragma unroll
    for (int m = 0; m < 4; ++m)
        #pragma unroll
        for (int n = 0; n < 2; ++n)
            c[m][n] = (f32x4){0.f, 0.f, 0.f, 0.f};

    #pragma unroll
    for (int ks = 0; ks < 4; ++ks) {       // K = 128 = 4 * 32
        int slot = ks * 4 + lg;
        bf16x8 a[4], b[2];
        #pragma unroll
        for (int m = 0; m < 4; ++m) {
            int r = wr * 64 + m * 16 + lr;
            a[m] = *reinterpret_cast<const bf16x8*>(&lds[r * 16 + (slot ^ (r & 7))]);
        }
        #pragma unroll
        for (int n = 0; n < 2; ++n) {
            int r = wc * 32 + n * 16 + lr;
            b[n] = *reinterpret_cast<const bf16x8*>(&lds[2048 + r * 16 + (slot ^ (r & 7))]);
        }
        #pragma unroll
        for (int m = 0; m < 4; ++m)
            #pragma unroll
            for (int n = 0; n < 2; ++n)
                c[m][n] = __builtin_amdgcn_mfma_f32_16x16x32_bf16(a[m], b[n], c[m][n], 0, 0, 0);
    }

    // ---- epilogue: e = exp(-2*(2-2g)) = exp2(C1*g + C0), packed fp32 math ----
    const float C1 = 4.0f * 1.4426950408889634f;
    const float C0 = -4.0f * 1.4426950408889634f;
    bool diag = (ti == tj);
    float psum;
    if (!diag) {
        f32x2 acc2 = (f32x2){0.f, 0.f};
        #pragma unroll
        for (int m = 0; m < 4; ++m)
            #pragma unroll
            for (int n = 0; n < 2; ++n) {
                f32x4 g = c[m][n];
                f32x2 glo = (f32x2){g[0], g[1]};
                f32x2 ghi = (f32x2){g[2], g[3]};
                f32x2 wlo = glo * C1 + C0;          // v_pk_fma_f32
                f32x2 whi = ghi * C1 + C0;
                f32x2 elo = (f32x2){exp2f(wlo.x), exp2f(wlo.y)};
                f32x2 ehi = (f32x2){exp2f(whi.x), exp2f(whi.y)};
                acc2 += elo;                        // v_pk_add_f32
                acc2 += ehi;
            }
        psum = acc2.x + acc2.y;
    } else {
        // diagonal tile: strict upper only; keep the clamp (g_ii ~ 1)
        psum = 0.0f;
        int crow0 = wr * 64 + lg * 4;      // C layout: row=(lane>>4)*4+reg
        int ccol0 = wc * 32 + lr;          //           col=lane&15
        #pragma unroll
        for (int m = 0; m < 4; ++m)
            #pragma unroll
            for (int n = 0; n < 2; ++n)
                #pragma unroll
                for (int r = 0; r < 4; ++r) {
                    float g = c[m][n][r];
                    float w = fminf(fmaf(g, C1, C0), 0.0f);
                    float e = exp2f(w);
                    int lrow = crow0 + m * 16 + r;
                    int lcol = ccol0 + n * 16;
                    psum += (lcol > lrow) ? e : 0.0f;
                }
    }
    #pragma unroll
    for (int off = 32; off; off >>= 1) psum += __shfl_xor(psum, off);

    if (lane == 0) red[wid] = psum;
    __syncthreads();
    if (tid == 0) {
        float s = 0.0f;
        #pragma unroll
        for (int w = 0; w < 8; ++w) s += red[w];
        unif_part[bid] = s;
    }
}

// Single block: sum all partials in double, emit final scalar.
__global__ __launch_bounds__(256) void finalize(
        const float* __restrict__ align_part,   // [2048]
        const float* __restrict__ unif_part,    // [2*TRI]
        float* __restrict__ out) {
    int tid = threadIdx.x;
    double a = 0.0, qs = 0.0, ks = 0.0;
    for (int i = tid; i < 2048; i += 256) a  += (double)align_part[i];
    for (int i = tid; i < TRI;  i += 256) qs += (double)unif_part[i];
    for (int i = tid; i < TRI;  i += 256) ks += (double)unif_part[TRI + i];

    __shared__ double sa[256], sq[256], sk[256];
    sa[tid] = a; sq[tid] = qs; sk[tid] = ks;
    __syncthreads();
    for (int s = 128; s; s >>= 1) {
        if (tid < s) {
            sa[tid] += sa[tid + s];
            sq[tid] += sq[tid + s];
            sk[tid] += sk[tid + s];
        }
        __syncthreads();
    }
    if (tid == 0) {
        const double npairs = (double)NROWS * (NROWS - 1) / 2.0;
        double align = sa[0] / (double)NROWS;
        double lq = log(sq[0] / npairs);
        double lk = log(sk[0] / npairs);
        out[0] = (float)(align + 0.5 * (lq + lk));   // LAMDA = 1
    }
}

extern "C" void kernel_launch(void* const* d_in, const int* in_sizes, int n_in,
                              void* d_out, int out_size, void* d_ws, size_t ws_size,
                              hipStream_t stream) {
    const float* q = (const float*)d_in[0];
    const float* k = (const float*)d_in[1];
    char* ws = (char*)d_ws;
    unsigned int* qn = (unsigned int*)ws;                          // 2 MiB bf16
    unsigned int* kn = (unsigned int*)(ws + (size_t)2 * 1024 * 1024);
    float* align_part = (float*)(ws + (size_t)4 * 1024 * 1024);            // 2048 f32
    float* unif_part  = (float*)(ws + (size_t)4 * 1024 * 1024 + 16384);    // 4160 f32
    float* out = (float*)d_out;

    norm_kernel<<<NROWS / 4, 256, 0, stream>>>(q, k, qn, kn, align_part);
    gram_kernel<<<2 * TRI, 512, 0, stream>>>((const uint4*)qn, (const uint4*)kn, unif_part);
    finalize<<<1, 256, 0, stream>>>(align_part, unif_part, out);
}

// Round 4
// 97.035 us; speedup vs baseline: 3.7876x; 1.1006x over previous
//
#include <hip/hip_runtime.h>
#include <math.h>

#define NROWS 8192
#define DIM   128            // row length (fp32 in, bf16 staged)
#define NT    64             // 8192 / 128 tiles per side
#define TRI   2080           // NT*(NT+1)/2 upper-tri tiles incl diag

typedef __attribute__((ext_vector_type(8))) __bf16 bf16x8;
typedef __attribute__((ext_vector_type(4))) float  f32x4;

__device__ __forceinline__ unsigned short f2bf(float f) {
    unsigned int u = __float_as_uint(f);
    u += 0x7fffu + ((u >> 16) & 1u);   // round-to-nearest-even
    return (unsigned short)(u >> 16);
}

// One wave per row: normalize q-row and k-row, write bf16, per-block align partial.
__global__ __launch_bounds__(256) void norm_kernel(
        const float* __restrict__ q, const float* __restrict__ k,
        unsigned int* __restrict__ qn, unsigned int* __restrict__ kn,
        float* __restrict__ align_part) {
    int wave = threadIdx.x >> 6;
    int lane = threadIdx.x & 63;
    int row  = blockIdx.x * 4 + wave;      // grid = 2048 blocks * 4 waves

    const float2 qv = reinterpret_cast<const float2*>(q)[row * 64 + lane];
    const float2 kv = reinterpret_cast<const float2*>(k)[row * 64 + lane];

    float sq = qv.x * qv.x + qv.y * qv.y;
    float sk = kv.x * kv.x + kv.y * kv.y;
    #pragma unroll
    for (int off = 32; off; off >>= 1) {
        sq += __shfl_xor(sq, off);
        sk += __shfl_xor(sk, off);
    }
    float qi = 1.0f / fmaxf(sqrtf(sq), 1e-12f);
    float ki = 1.0f / fmaxf(sqrtf(sk), 1e-12f);
    float qx = qv.x * qi, qy = qv.y * qi;
    float kx = kv.x * ki, ky = kv.y * ki;

    qn[row * 64 + lane] = (unsigned int)f2bf(qx) | ((unsigned int)f2bf(qy) << 16);
    kn[row * 64 + lane] = (unsigned int)f2bf(kx) | ((unsigned int)f2bf(ky) << 16);

    float dx = qx - kx, dy = qy - ky;
    float d2 = dx * dx + dy * dy;
    #pragma unroll
    for (int off = 32; off; off >>= 1) d2 += __shfl_xor(d2, off);

    __shared__ float red[4];
    if (lane == 0) red[wave] = d2;
    __syncthreads();
    if (threadIdx.x == 0)
        align_part[blockIdx.x] = red[0] + red[1] + red[2] + red[3];
}

// One 128x128 Gram tile per block (upper-triangular tiles only), 8 waves (2x4).
// unif_part[bid] = sum_{i<j in tile} exp(-2*(2-2*g))
// exp via Schraudolph: exp2(w) ~= as_float((int)(2^23*w + (127-0.0574)*2^23))
// fused from g: u = g*K1 + K0, e = as_float((int)u); 3 full-rate VALU/elem.
__global__ __launch_bounds__(512) void gram_kernel(
        const uint4* __restrict__ qn, const uint4* __restrict__ kn,
        float* __restrict__ unif_part) {
    __shared__ uint4 lds[4096];            // A: [0,2048) B: [2048,4096), 64 KiB
    __shared__ float red[8];

    int bid = blockIdx.x;
    int mat = 0, t = bid;
    if (t >= TRI) { mat = 1; t -= TRI; }
    int ti = 0, rem = t;
    while (rem >= NT - ti) { rem -= NT - ti; ++ti; }
    int tj = ti + rem;
    const uint4* __restrict__ x = mat ? kn : qn;

    int tid = threadIdx.x;
    // ---- stage both row-panels, XOR-swizzled (slot ^ (row&15)) ----
    {
        int s = tid & 15;                  // 16B slot within 256B row
        int rb = tid >> 4;                 // 0..31
        #pragma unroll
        for (int it = 0; it < 4; ++it) {
            int r = it * 32 + rb;
            int sw = s ^ (r & 15);
            lds[r * 16 + sw]        = x[(ti * 128 + r) * 16 + s];
            lds[2048 + r * 16 + sw] = x[(tj * 128 + r) * 16 + s];
        }
    }
    __syncthreads();

    int wid = tid >> 6, lane = tid & 63;
    int wr = wid >> 2, wc = wid & 3;       // 2x4 wave grid, each 64x32
    int lr = lane & 15, lg = lane >> 4;    // frag row / k-group

    f32x4 c[4][2];
    #pragma unroll
    for (int m = 0; m < 4; ++m)
        #pragma unroll
        for (int n = 0; n < 2; ++n)
            c[m][n] = (f32x4){0.f, 0.f, 0.f, 0.f};

    #pragma unroll
    for (int ks = 0; ks < 4; ++ks) {       // K = 128 = 4 * 32
        int slot = ks * 4 + lg;
        bf16x8 a[4], b[2];
        #pragma unroll
        for (int m = 0; m < 4; ++m) {
            int r = wr * 64 + m * 16 + lr;
            a[m] = *reinterpret_cast<const bf16x8*>(&lds[r * 16 + (slot ^ (r & 15))]);
        }
        #pragma unroll
        for (int n = 0; n < 2; ++n) {
            int r = wc * 32 + n * 16 + lr;
            b[n] = *reinterpret_cast<const bf16x8*>(&lds[2048 + r * 16 + (slot ^ (r & 15))]);
        }
        #pragma unroll
        for (int m = 0; m < 4; ++m)
            #pragma unroll
            for (int n = 0; n < 2; ++n)
                c[m][n] = __builtin_amdgcn_mfma_f32_16x16x32_bf16(a[m], b[n], c[m][n], 0, 0, 0);
    }

    // ---- epilogue: e = exp2(K*(g-1)) via Schraudolph fast exp ----
    // K1 = 4*log2(e)*2^23 ; B = (127 - 0.05744)*2^23 (zero-mean bias) ; K0 = B - K1
    const float K1 = 4.0f * 1.4426950408889634f * 8388608.0f;
    const float B  = 1065353216.0f - 0.05744f * 8388608.0f;
    const float K0 = B - K1;
    bool diag = (ti == tj);
    float psum = 0.0f;
    if (!diag) {
        #pragma unroll
        for (int m = 0; m < 4; ++m)
            #pragma unroll
            for (int n = 0; n < 2; ++n) {
                f32x4 g = c[m][n];
                #pragma unroll
                for (int r = 0; r < 4; ++r) {
                    float u = fmaf(g[r], K1, K0);
                    psum += __int_as_float((int)u);
                }
            }
    } else {
        // diagonal tile: strict upper only; clamp u at w=0 point (g_ii ~ 1)
        int crow0 = wr * 64 + lg * 4;      // C layout: row=(lane>>4)*4+reg
        int ccol0 = wc * 32 + lr;          //           col=lane&15
        #pragma unroll
        for (int m = 0; m < 4; ++m)
            #pragma unroll
            for (int n = 0; n < 2; ++n)
                #pragma unroll
                for (int r = 0; r < 4; ++r) {
                    float u = fminf(fmaf(c[m][n][r], K1, K0), B);
                    float e = __int_as_float((int)u);
                    int lrow = crow0 + m * 16 + r;
                    int lcol = ccol0 + n * 16;
                    psum += (lcol > lrow) ? e : 0.0f;
                }
    }
    #pragma unroll
    for (int off = 32; off; off >>= 1) psum += __shfl_xor(psum, off);

    if (lane == 0) red[wid] = psum;
    __syncthreads();
    if (tid == 0) {
        float s = 0.0f;
        #pragma unroll
        for (int w = 0; w < 8; ++w) s += red[w];
        unif_part[bid] = s;
    }
}

// Single block: sum all partials in double, emit final scalar.
__global__ __launch_bounds__(256) void finalize(
        const float* __restrict__ align_part,   // [2048]
        const float* __restrict__ unif_part,    // [2*TRI]
        float* __restrict__ out) {
    int tid = threadIdx.x;
    double a = 0.0, qs = 0.0, ks = 0.0;
    for (int i = tid; i < 2048; i += 256) a  += (double)align_part[i];
    for (int i = tid; i < TRI;  i += 256) qs += (double)unif_part[i];
    for (int i = tid; i < TRI;  i += 256) ks += (double)unif_part[TRI + i];

    __shared__ double sa[256], sq[256], sk[256];
    sa[tid] = a; sq[tid] = qs; sk[tid] = ks;
    __syncthreads();
    for (int s = 128; s; s >>= 1) {
        if (tid < s) {
            sa[tid] += sa[tid + s];
            sq[tid] += sq[tid + s];
            sk[tid] += sk[tid + s];
        }
        __syncthreads();
    }
    if (tid == 0) {
        const double npairs = (double)NROWS * (NROWS - 1) / 2.0;
        double align = sa[0] / (double)NROWS;
        double lq = log(sq[0] / npairs);
        double lk = log(sk[0] / npairs);
        out[0] = (float)(align + 0.5 * (lq + lk));   // LAMDA = 1
    }
}

extern "C" void kernel_launch(void* const* d_in, const int* in_sizes, int n_in,
                              void* d_out, int out_size, void* d_ws, size_t ws_size,
                              hipStream_t stream) {
    const float* q = (const float*)d_in[0];
    const float* k = (const float*)d_in[1];
    char* ws = (char*)d_ws;
    unsigned int* qn = (unsigned int*)ws;                          // 2 MiB bf16
    unsigned int* kn = (unsigned int*)(ws + (size_t)2 * 1024 * 1024);
    float* align_part = (float*)(ws + (size_t)4 * 1024 * 1024);            // 2048 f32
    float* unif_part  = (float*)(ws + (size_t)4 * 1024 * 1024 + 16384);    // 4160 f32
    float* out = (float*)d_out;

    norm_kernel<<<NROWS / 4, 256, 0, stream>>>(q, k, qn, kn, align_part);
    gram_kernel<<<2 * TRI, 512, 0, stream>>>((const uint4*)qn, (const uint4*)kn, unif_part);
    finalize<<<1, 256, 0, stream>>>(align_part, unif_part, out);
}